// Round 10
// baseline (809.999 us; speedup 1.0000x reference)
//
#include <hip/hip_runtime.h>
#include <hip/hip_fp16.h>

constexpr int N = 50000;        // nodes
constexpr int D = 64;           // feature dim
constexpr int E = 1600000;      // edges
constexpr int NBUCK = (N + 127) / 128;   // 391 buckets of 128 nodes (dst>>7)
constexpr int CAP = 4608;                // bucket window capacity (mean 4092, sigma~64 -> 8s slack)
constexpr int CPT = 16;                  // edges per thread in k_bucket
constexpr int BUCK_BLOCKS = (E + 256 * CPT - 1) / (256 * CPT);  // 391

// ---------------------------------------------------------------------------
// K0: init per-bucket window cursors (cursor[b] = b*CAP)
__global__ void k_init(int* __restrict__ cursor) {
    int t = threadIdx.x;
    if (t < NBUCK) cursor[t] = t * CAP;
}

// K1: privatized counting-sort scatter -> fixed-capacity bucket windows.
// packed = dst<<16 | src (both < 65536). Per-(block,bucket) chunks contiguous.
__global__ void k_bucket(const int* __restrict__ src, const int* __restrict__ dst,
                         int* __restrict__ cursor, unsigned* __restrict__ packed) {
    __shared__ int lh[NBUCK];
    __shared__ int lb[NBUCK];
    int tid = threadIdx.x;
    for (int i = tid; i < NBUCK; i += 256) lh[i] = 0;
    __syncthreads();
    int base_e = blockIdx.x * (256 * CPT);
    unsigned pk[CPT];
    int bn[CPT], rk[CPT];
#pragma unroll
    for (int i = 0; i < CPT; ++i) {
        int e = base_e + i * 256 + tid;
        if (e < E) {
            int d = dst[e];
            int s = src[e];
            bn[i] = d >> 7;
            pk[i] = ((unsigned)d << 16) | (unsigned)s;
            rk[i] = atomicAdd(&lh[bn[i]], 1);
        } else bn[i] = -1;
    }
    __syncthreads();
    for (int i = tid; i < NBUCK; i += 256) {
        int c = lh[i];
        lb[i] = c ? atomicAdd(&cursor[i], c) : 0;   // one global atomic per bucket/block
    }
    __syncthreads();
#pragma unroll
    for (int i = 0; i < CPT; ++i)
        if (bn[i] >= 0) packed[lb[bn[i]] + rk[i]] = pk[i];
}

// K2: per-bucket degree histogram -> norm (no scan, no fill)
__global__ void k_degnorm(const int* __restrict__ cursor, const unsigned* __restrict__ packed,
                          float* __restrict__ norm) {
    __shared__ int cnt[128];
    int b = blockIdx.x, tid = threadIdx.x;
    if (tid < 128) cnt[tid] = 0;
    __syncthreads();
    int beg = b * CAP;
    int end = cursor[b];
    for (int j = beg + tid; j < end; j += 512)
        atomicAdd(&cnt[(packed[j] >> 16) & 127], 1);
    __syncthreads();
    if (tid < 128) {
        int node = b * 128 + tid;
        if (node < N) norm[node] = cnt[tid] ? rsqrtf((float)cnt[tid]) : 0.0f;
    }
}

// K3: h2[row][d] = (sum_k x[row][k] * W[k][d]) * norm[row], stored fp16
__global__ void k_gemm(const float* __restrict__ x, const float* __restrict__ W,
                       const float* __restrict__ norm, __half* __restrict__ h2) {
    __shared__ float Wl[64 * 64];
    __shared__ float xs[16][64];
    int tid = threadIdx.x;
    const float4* W4 = (const float4*)W;
    float4* Wl4 = (float4*)Wl;
    Wl4[tid] = W4[tid];
    int r = tid >> 6, d = tid & 63;
    int row = blockIdx.x * 16 + r;
    xs[r][d] = x[row * 64 + d];
    __syncthreads();
    float a = 0.0f;
#pragma unroll
    for (int k = 0; k < 64; ++k) a = fmaf(xs[r][k], Wl[k * 64 + d], a);
    h2[row * 64 + d] = __float2half(a * norm[row]);
}

// K4: fused aggregate directly from packed (no CSR) + norm + bias + softplus.
// One block (16 waves) per 128-node bucket; 32 KB LDS fp32 accumulator.
// Each wave handles one edge pair per step: lanes 0-31 edge A, 32-63 edge B;
// half2 gather (128B/wave-instr), ds_add_f32 into acc rows. Lane-parallel
// float4 epilogue.
__global__ void k_agg(const int* __restrict__ cursor, const unsigned* __restrict__ packed,
                      const __half* __restrict__ h2, const float* __restrict__ norm,
                      const float* __restrict__ bias, float* __restrict__ out) {
    __shared__ float acc[128 * 64];        // 32 KB
    int b = blockIdx.x, tid = threadIdx.x;
    int w = tid >> 6;                      // wave 0..15
    int lane = tid & 63;
    int h = lane >> 5;                     // which edge of the pair
    int fl = lane & 31;                    // feature-pair index
    float4* acc4 = (float4*)acc;
#pragma unroll
    for (int i = 0; i < 2; ++i) acc4[tid + i * 1024] = make_float4(0.f, 0.f, 0.f, 0.f);
    __syncthreads();
    int beg = b * CAP;
    int end = cursor[b];
    int cnt = end - beg;
    int nFull = cnt >> 1;                  // full edge pairs
    const __half2* h2v = (const __half2*)h2;   // row stride 32
    int p = w;
    for (; p + 16 < nFull; p += 32) {      // 2 pairs (4 edges) per iteration
        unsigned u0 = packed[beg + 2 * p + h];
        unsigned u1 = packed[beg + 2 * (p + 16) + h];
        int s0 = u0 & 0xFFFFu, l0 = (u0 >> 16) & 127;
        int s1 = u1 & 0xFFFFu, l1 = (u1 >> 16) & 127;
        float2 f0 = __half22float2(h2v[s0 * 32 + fl]);
        float2 f1 = __half22float2(h2v[s1 * 32 + fl]);
        atomicAdd(&acc[l0 * 64 + 2 * fl], f0.x);
        atomicAdd(&acc[l0 * 64 + 2 * fl + 1], f0.y);
        atomicAdd(&acc[l1 * 64 + 2 * fl], f1.x);
        atomicAdd(&acc[l1 * 64 + 2 * fl + 1], f1.y);
    }
    for (; p < nFull; p += 16) {           // remaining pairs
        unsigned u = packed[beg + 2 * p + h];
        int s = u & 0xFFFFu, l = (u >> 16) & 127;
        float2 f = __half22float2(h2v[s * 32 + fl]);
        atomicAdd(&acc[l * 64 + 2 * fl], f.x);
        atomicAdd(&acc[l * 64 + 2 * fl + 1], f.y);
    }
    if ((cnt & 1) && w == 0 && h == 0) {   // odd final edge: lanes 0-31 of wave 0
        unsigned u = packed[end - 1];
        int s = u & 0xFFFFu, l = (u >> 16) & 127;
        float2 f = __half22float2(h2v[s * 32 + fl]);
        atomicAdd(&acc[l * 64 + 2 * fl], f.x);
        atomicAdd(&acc[l * 64 + 2 * fl + 1], f.y);
    }
    __syncthreads();
    // epilogue: 128 nodes x 64 feats = 2048 float4; 2 per thread, lane-parallel
#pragma unroll
    for (int i = 0; i < 2; ++i) {
        int idx4 = tid + i * 1024;         // float4 index
        int local = idx4 >> 4;             // node within bucket
        int f4 = idx4 & 15;                // float4 within row
        int node = b * 128 + local;
        if (node < N) {
            float4 a = acc4[idx4];
            float nrm = norm[node];
            float4 bs = ((const float4*)bias)[f4];
            float v0 = a.x * nrm + bs.x;
            float v1 = a.y * nrm + bs.y;
            float v2 = a.z * nrm + bs.z;
            float v3 = a.w * nrm + bs.w;
            float4 o;
            o.x = fmaxf(v0, 0.0f) + log1pf(expf(-fabsf(v0)));
            o.y = fmaxf(v1, 0.0f) + log1pf(expf(-fabsf(v1)));
            o.z = fmaxf(v2, 0.0f) + log1pf(expf(-fabsf(v2)));
            o.w = fmaxf(v3, 0.0f) + log1pf(expf(-fabsf(v3)));
            ((float4*)out)[node * 16 + f4] = o;
        }
    }
}

extern "C" void kernel_launch(void* const* d_in, const int* in_sizes, int n_in,
                              void* d_out, int out_size, void* d_ws, size_t ws_size,
                              hipStream_t stream) {
    // inputs: t(f32,1), x(f32,N*D), weight(f32,D*D), bias(f32,D), src(i32,E), dst(i32,E)
    const float* x    = (const float*)d_in[1];
    const float* W    = (const float*)d_in[2];
    const float* bias = (const float*)d_in[3];
    const int* src = (const int*)d_in[4];
    const int* dst = (const int*)d_in[5];
    float* out = (float*)d_out;

    // workspace layout (~13.8 MB; poisoned 0xAA every call — every buffer is
    // fully written before it is read)
    char* ws = (char*)d_ws;
    __half*   h2     = (__half*)(ws);                  // 6.4 MB
    unsigned* packed = (unsigned*)(ws + 6400000);      // NBUCK*CAP*4 = 7.21 MB
    float*    norm   = (float*)(ws + 13606912);        // N*4
    int*      cursor = (int*)(ws + 13806912);          // NBUCK*4

    k_init   <<<1, 512, 0, stream>>>(cursor);
    k_bucket <<<BUCK_BLOCKS, 256, 0, stream>>>(src, dst, cursor, packed);
    k_degnorm<<<NBUCK, 512, 0, stream>>>(cursor, packed, norm);
    k_gemm   <<<(N + 15) / 16, 1024, 0, stream>>>(x, W, norm, h2);
    k_agg    <<<NBUCK, 1024, 0, stream>>>(cursor, packed, h2, norm, bias, out);
}

// Round 11
// 165.912 us; speedup vs baseline: 4.8821x; 4.8821x over previous
//
#include <hip/hip_runtime.h>
#include <hip/hip_fp16.h>

constexpr int N = 50000;        // nodes
constexpr int D = 64;           // feature dim
constexpr int E = 1600000;      // edges
constexpr int NBUCK = (N + 127) / 128;   // 391 buckets of 128 nodes (dst>>7)
constexpr int CAP = 4608;                // bucket window capacity (mean 4092)
constexpr int BTHREADS = 512;
constexpr int CPT = 8;                   // edges per thread in k_bucket
constexpr int EPB = BTHREADS * CPT;      // 4096 edges per block
constexpr int BUCK_BLOCKS = (E + EPB - 1) / EPB;  // 391

// ---------------------------------------------------------------------------
// K0: init per-bucket window cursors (cursor[b] = b*CAP)
__global__ void k_init(int* __restrict__ cursor) {
    int t = threadIdx.x;
    if (t < NBUCK) cursor[t] = t * CAP;
}

// K1: privatized counting-sort scatter -> fixed-capacity bucket windows.
// packed = dst<<16 | src (both < 65536); bucket = packed>>23.
// Edges are permuted into bucket-sorted order in LDS first, so global writes
// are contiguous runs (~21 edges) per bucket chunk instead of full scatter.
__global__ void k_bucket(const int* __restrict__ src, const int* __restrict__ dst,
                         int* __restrict__ cursor, unsigned* __restrict__ packed) {
    __shared__ int lh[NBUCK];
    __shared__ int scan[BTHREADS];
    __shared__ int lb[NBUCK];
    __shared__ unsigned stage[EPB];      // 16 KB
    int tid = threadIdx.x;
    for (int i = tid; i < NBUCK; i += BTHREADS) lh[i] = 0;
    __syncthreads();
    int base_e = blockIdx.x * EPB;
    unsigned pk[CPT];
    int bn[CPT], rk[CPT];
#pragma unroll
    for (int i = 0; i < CPT; ++i) {
        int e = base_e + i * BTHREADS + tid;
        if (e < E) {
            int d = dst[e];
            int s = src[e];
            bn[i] = d >> 7;
            pk[i] = ((unsigned)d << 16) | (unsigned)s;
            rk[i] = atomicAdd(&lh[bn[i]], 1);
        } else bn[i] = -1;
    }
    __syncthreads();
    // inclusive scan of lh over NBUCK (<=512)
    scan[tid] = (tid < NBUCK) ? lh[tid] : 0;
    __syncthreads();
    for (int off = 1; off < BTHREADS; off <<= 1) {
        int v = (tid >= off) ? scan[tid - off] : 0;
        __syncthreads();
        scan[tid] += v;
        __syncthreads();
    }
    if (tid < NBUCK) {
        int c = lh[tid];
        lb[tid] = c ? atomicAdd(&cursor[tid], c) : 0;  // one global atomic per bucket/block
    }
    __syncthreads();
#pragma unroll
    for (int i = 0; i < CPT; ++i) {
        if (bn[i] >= 0) {
            int eb = (bn[i] == 0) ? 0 : scan[bn[i] - 1];
            stage[eb + rk[i]] = pk[i];   // LDS scatter into bucket-sorted order
        }
    }
    __syncthreads();
    int tot = scan[NBUCK - 1];
    for (int j = tid; j < tot; j += BTHREADS) {
        unsigned v = stage[j];
        int bk = v >> 23;                // dst>>7
        int eb = (bk == 0) ? 0 : scan[bk - 1];
        packed[lb[bk] + (j - eb)] = v;   // contiguous within each chunk
    }
}

// K2: one block (512 thr) per 128-node bucket — LDS hist + scan -> rowptr/
// rowend/norm; fill node-sorted u16 src into LDS stage, then coalesced
// uint copy-out to the bucket's CSR window.
__global__ void k_csr(const int* __restrict__ cursor, const unsigned* __restrict__ packed,
                      unsigned short* __restrict__ csr, int* __restrict__ rowptr,
                      int* __restrict__ rowend, float* __restrict__ norm) {
    __shared__ int cnt[128];
    __shared__ int sm[128];
    __shared__ int cur[128];
    __shared__ unsigned short stage[CAP];   // 9 KB
    int b = blockIdx.x, tid = threadIdx.x;
    if (tid < 128) cnt[tid] = 0;
    __syncthreads();
    int beg = b * CAP;
    int m = cursor[b] - beg;                // edges in this bucket
    for (int j = tid; j < m; j += 512)
        atomicAdd(&cnt[(packed[beg + j] >> 16) & 127], 1);
    __syncthreads();
    if (tid < 128) sm[tid] = cnt[tid];
    __syncthreads();
    for (int off = 1; off < 128; off <<= 1) {
        int v = 0;
        if (tid < 128 && tid >= off) v = sm[tid - off];
        __syncthreads();
        if (tid < 128) sm[tid] += v;
        __syncthreads();
    }
    if (tid < 128) {
        int excl = (tid == 0) ? 0 : sm[tid - 1];
        int node = b * 128 + tid;
        if (node < N) {
            rowptr[node] = beg + excl;
            rowend[node] = beg + sm[tid];
            norm[node] = cnt[tid] ? rsqrtf((float)cnt[tid]) : 0.0f;
        }
        cur[tid] = excl;                    // local offset within stage
    }
    __syncthreads();
    for (int j = tid; j < m; j += 512) {
        unsigned p = packed[beg + j];
        int slot = atomicAdd(&cur[(p >> 16) & 127], 1);
        stage[slot] = (unsigned short)(p & 0xFFFFu);
    }
    __syncthreads();
    unsigned* du = (unsigned*)(csr + beg);  // beg even, base 4B-aligned
    const unsigned* su = (const unsigned*)stage;
    int mu = m >> 1;
    for (int k = tid; k < mu; k += 512) du[k] = su[k];
    if ((m & 1) && tid == 0) csr[beg + m - 1] = stage[m - 1];
}

// K3: h2[row][d] = (sum_k x[row][k] * W[k][d]) * norm[row], stored fp16
__global__ void k_gemm(const float* __restrict__ x, const float* __restrict__ W,
                       const float* __restrict__ norm, __half* __restrict__ h2) {
    __shared__ float Wl[64 * 64];
    __shared__ float xs[16][64];
    int tid = threadIdx.x;
    const float4* W4 = (const float4*)W;
    float4* Wl4 = (float4*)Wl;
    Wl4[tid] = W4[tid];
    int r = tid >> 6, d = tid & 63;
    int row = blockIdx.x * 16 + r;
    xs[r][d] = x[row * 64 + d];
    __syncthreads();
    float a = 0.0f;
#pragma unroll
    for (int k = 0; k < 64; ++k) a = fmaf(xs[r][k], Wl[k * 64 + d], a);
    h2[row * 64 + d] = __float2half(a * norm[row]);
}

// K4: fused aggregate + dst-norm + bias + softplus (R8's 47us version).
// One wave per node; lanes 0-31 even edges, 32-63 odd; half2 loads (one wave
// op covers two 128B rows); fp32 register accum; shfl_xor(32) combine.
__global__ void k_aggregate(const int* __restrict__ rowptr, const int* __restrict__ rowend,
                            const unsigned short* __restrict__ csr,
                            const __half* __restrict__ h2, const float* __restrict__ norm,
                            const float* __restrict__ bias, float* __restrict__ out) {
    int node = blockIdx.x * 4 + (threadIdx.x >> 6);
    int lane = threadIdx.x & 63;
    int half = lane >> 5;          // which edge of the pair
    int fl = lane & 31;            // feature-pair index (features 2fl, 2fl+1)
    const __half2* h2v = (const __half2*)h2;   // row stride 32
    int beg = rowptr[node];
    int end = rowend[node];
    float ax = 0.0f, ay = 0.0f, bx = 0.0f, by = 0.0f;
    int j = beg;
    for (; j + 7 < end; j += 8) {            // 8 edges per wave iteration
        int s0 = csr[j + half];
        int s1 = csr[j + 2 + half];
        int s2 = csr[j + 4 + half];
        int s3 = csr[j + 6 + half];
        float2 v0 = __half22float2(h2v[s0 * 32 + fl]);
        float2 v1 = __half22float2(h2v[s1 * 32 + fl]);
        float2 v2 = __half22float2(h2v[s2 * 32 + fl]);
        float2 v3 = __half22float2(h2v[s3 * 32 + fl]);
        ax += v0.x + v2.x;  ay += v0.y + v2.y;
        bx += v1.x + v3.x;  by += v1.y + v3.y;
    }
    for (; j + 1 < end; j += 2) {            // pair tail
        int s = csr[j + half];
        float2 v = __half22float2(h2v[s * 32 + fl]);
        ax += v.x;  ay += v.y;
    }
    if (j < end && half == 0) {              // odd final edge
        int s = csr[j];
        float2 v = __half22float2(h2v[s * 32 + fl]);
        ax += v.x;  ay += v.y;
    }
    ax += bx;  ay += by;
    ax += __shfl_xor(ax, 32, 64);            // combine the two half-waves
    ay += __shfl_xor(ay, 32, 64);
    if (half == 0) {
        float nrm = norm[node];
        float2 bs = ((const float2*)bias)[fl];
        float vx = ax * nrm + bs.x;
        float vy = ay * nrm + bs.y;
        float2 o;
        o.x = fmaxf(vx, 0.0f) + log1pf(expf(-fabsf(vx)));
        o.y = fmaxf(vy, 0.0f) + log1pf(expf(-fabsf(vy)));
        ((float2*)out)[node * 32 + fl] = o;
    }
}

extern "C" void kernel_launch(void* const* d_in, const int* in_sizes, int n_in,
                              void* d_out, int out_size, void* d_ws, size_t ws_size,
                              hipStream_t stream) {
    // inputs: t(f32,1), x(f32,N*D), weight(f32,D*D), bias(f32,D), src(i32,E), dst(i32,E)
    const float* x    = (const float*)d_in[1];
    const float* W    = (const float*)d_in[2];
    const float* bias = (const float*)d_in[3];
    const int* src = (const int*)d_in[4];
    const int* dst = (const int*)d_in[5];
    float* out = (float*)d_out;

    // workspace layout (~17.9 MB; poisoned 0xAA every call — every buffer is
    // fully written before it is read)
    char* ws = (char*)d_ws;
    __half*         h2     = (__half*)(ws);                     // 6.4 MB
    unsigned*       packed = (unsigned*)(ws + 6400000);         // NBUCK*CAP*4 = 7.21 MB
    unsigned short* csr    = (unsigned short*)(ws + 13606912);  // NBUCK*CAP*2 = 3.6 MB
    int*            rowptr = (int*)(ws + 17210368);             // N*4
    int*            rowend = (int*)(ws + 17410368);             // N*4
    float*          norm   = (float*)(ws + 17610368);           // N*4
    int*            cursor = (int*)(ws + 17810368);             // NBUCK*4

    k_init     <<<1, 512, 0, stream>>>(cursor);
    k_bucket   <<<BUCK_BLOCKS, BTHREADS, 0, stream>>>(src, dst, cursor, packed);
    k_csr      <<<NBUCK, 512, 0, stream>>>(cursor, packed, csr, rowptr, rowend, norm);
    k_gemm     <<<(N + 15) / 16, 1024, 0, stream>>>(x, W, norm, h2);
    k_aggregate<<<(N + 3) / 4, 256, 0, stream>>>(rowptr, rowend, csr, h2, norm, bias, out);
}